// Round 1
// baseline (1325.240 us; speedup 1.0000x reference)
//
#include <hip/hip_runtime.h>
#include <math.h>

#define N_NODES 100000
#define N_EDGES 1600000
#define D_IN 256
#define D_H 128
#define D_OUT 32

// ---------------- degree / norm ----------------
__global__ void k_deg_init(float* deg, int n) {
    int i = blockIdx.x * blockDim.x + threadIdx.x;
    if (i < n) deg[i] = 1.0f;  // self-loop
}

__global__ void k_deg_count(const int* __restrict__ col, float* deg, int e) {
    int i = blockIdx.x * blockDim.x + threadIdx.x;
    if (i < e) atomicAdd(&deg[col[i]], 1.0f);
}

__global__ void k_dinv(float* deg, int n) {
    int i = blockIdx.x * blockDim.x + threadIdx.x;
    if (i < n) deg[i] = rsqrtf(deg[i]);
}

// ---------------- GEMM1: x[N,256] @ W1[256,128] -> hx[N,128] ----------------
#define G1_NODES 8
__global__ __launch_bounds__(128) void k_gemm1(const float* __restrict__ x,
                                               const float* __restrict__ W,
                                               float* __restrict__ hx, int n) {
    __shared__ float xs[G1_NODES][D_IN];
    const int tid = threadIdx.x;          // 0..127
    const int base = blockIdx.x * G1_NODES;
    for (int i = tid; i < G1_NODES * D_IN; i += 128) {
        int r = i / D_IN, c = i - r * D_IN;
        int node = base + r;
        xs[r][c] = (node < n) ? x[(long long)node * D_IN + c] : 0.0f;
    }
    __syncthreads();
    float acc[G1_NODES];
#pragma unroll
    for (int j = 0; j < G1_NODES; j++) acc[j] = 0.0f;
    for (int k = 0; k < D_IN; k++) {
        float w = W[k * D_H + tid];       // coalesced; W1 L2-resident
#pragma unroll
        for (int j = 0; j < G1_NODES; j++) acc[j] += xs[j][k] * w;
    }
#pragma unroll
    for (int j = 0; j < G1_NODES; j++) {
        int node = base + j;
        if (node < n) hx[(long long)node * D_H + tid] = acc[j];
    }
}

// ---------------- layer-1 aggregation ----------------
__global__ void k_self1(const float* __restrict__ hx, const float* __restrict__ dinv,
                        float* __restrict__ agg, int n) {
    int idx = blockIdx.x * blockDim.x + threadIdx.x;
    if (idx < n * D_H) {
        int v = idx >> 7;                 // /128
        float di = dinv[v];
        agg[idx] = di * di * hx[idx];
    }
}

__global__ void k_edge1(const float* __restrict__ hx, const int* __restrict__ row,
                        const int* __restrict__ col, const float* __restrict__ dinv,
                        float* __restrict__ agg) {
    long long idx = (long long)blockIdx.x * blockDim.x + threadIdx.x;
    const long long total = (long long)N_EDGES * D_H;
    if (idx < total) {
        int e = (int)(idx >> 7);
        int d = (int)(idx & 127);
        int r = row[e], c = col[e];
        float w = dinv[r] * dinv[c];
        atomicAdd(&agg[(long long)c * D_H + d], w * hx[(long long)r * D_H + d]);
    }
}

__global__ void k_bias_relu(float* __restrict__ h, const float* __restrict__ b, int n) {
    int idx = blockIdx.x * blockDim.x + threadIdx.x;
    if (idx < n * D_H) {
        int d = idx & 127;
        h[idx] = fmaxf(h[idx] + b[d], 0.0f);
    }
}

// ---------------- GEMM2: h[N,128] @ W2[128,32] -> hx2[N,32] ----------------
#define G2_NODES 8
__global__ __launch_bounds__(256) void k_gemm2(const float* __restrict__ h,
                                               const float* __restrict__ W,
                                               float* __restrict__ hx2, int n) {
    __shared__ float Ws[D_H * D_OUT];     // 16 KB
    __shared__ float hs[G2_NODES][D_H];   // 4 KB
    const int tid = threadIdx.x;          // 0..255
    const int base = blockIdx.x * G2_NODES;
    for (int i = tid; i < D_H * D_OUT; i += 256) Ws[i] = W[i];
    for (int i = tid; i < G2_NODES * D_H; i += 256) {
        int r = i >> 7, c = i & 127;
        int node = base + r;
        hs[r][c] = (node < n) ? h[(long long)node * D_H + c] : 0.0f;
    }
    __syncthreads();
    int r = tid >> 5, d = tid & 31;
    int node = base + r;
    float acc = 0.0f;
#pragma unroll 8
    for (int k = 0; k < D_H; k++) acc += hs[r][k] * Ws[k * D_OUT + d];
    if (node < n) hx2[(long long)node * D_OUT + d] = acc;
}

// ---------------- layer-2 aggregation (into d_out) ----------------
__global__ void k_self2(const float* __restrict__ hx2, const float* __restrict__ dinv,
                        float* __restrict__ out, int n) {
    int idx = blockIdx.x * blockDim.x + threadIdx.x;
    if (idx < n * D_OUT) {
        int v = idx >> 5;
        float di = dinv[v];
        out[idx] = di * di * hx2[idx];
    }
}

__global__ void k_edge2(const float* __restrict__ hx2, const int* __restrict__ row,
                        const int* __restrict__ col, const float* __restrict__ dinv,
                        float* __restrict__ out) {
    long long idx = (long long)blockIdx.x * blockDim.x + threadIdx.x;
    const long long total = (long long)N_EDGES * D_OUT;
    if (idx < total) {
        int e = (int)(idx >> 5);
        int d = (int)(idx & 31);
        int r = row[e], c = col[e];
        float w = dinv[r] * dinv[c];
        atomicAdd(&out[(long long)c * D_OUT + d], w * hx2[(long long)r * D_OUT + d]);
    }
}

// ---------------- bias + log_softmax (in place on d_out) ----------------
__global__ void k_lsm(float* __restrict__ out, const float* __restrict__ b, int n) {
    int v = blockIdx.x * blockDim.x + threadIdx.x;
    if (v >= n) return;
    float vals[D_OUT];
    float mx = -INFINITY;
#pragma unroll
    for (int d = 0; d < D_OUT; d++) {
        float t = out[(long long)v * D_OUT + d] + b[d];
        vals[d] = t;
        mx = fmaxf(mx, t);
    }
    float s = 0.0f;
#pragma unroll
    for (int d = 0; d < D_OUT; d++) s += expf(vals[d] - mx);
    float lse = mx + logf(s);
#pragma unroll
    for (int d = 0; d < D_OUT; d++) out[(long long)v * D_OUT + d] = vals[d] - lse;
}

extern "C" void kernel_launch(void* const* d_in, const int* in_sizes, int n_in,
                              void* d_out, int out_size, void* d_ws, size_t ws_size,
                              hipStream_t stream) {
    const float* x  = (const float*)d_in[0];
    const float* W1 = (const float*)d_in[1];
    const float* b1 = (const float*)d_in[2];
    const float* W2 = (const float*)d_in[3];
    const float* b2 = (const float*)d_in[4];
    const int*   ei = (const int*)d_in[5];
    const int* row = ei;            // sources
    const int* col = ei + N_EDGES;  // targets
    float* out = (float*)d_out;

    // workspace layout (floats): dinv | hx | h | hx2  ~= 116 MB
    float* ws   = (float*)d_ws;
    float* dinv = ws;                               // N (padded to 102400)
    float* hx   = ws + 102400;                      // N*128
    float* h    = hx + (long long)N_NODES * D_H;    // N*128
    float* hx2  = h + (long long)N_NODES * D_H;     // N*32

    const int n = N_NODES, e = N_EDGES;

    k_deg_init<<<(n + 255) / 256, 256, 0, stream>>>(dinv, n);
    k_deg_count<<<(e + 255) / 256, 256, 0, stream>>>(col, dinv, e);
    k_dinv<<<(n + 255) / 256, 256, 0, stream>>>(dinv, n);

    k_gemm1<<<(n + G1_NODES - 1) / G1_NODES, 128, 0, stream>>>(x, W1, hx, n);

    k_self1<<<(n * D_H + 255) / 256, 256, 0, stream>>>(hx, dinv, h, n);
    {
        long long total = (long long)e * D_H;
        k_edge1<<<(int)((total + 255) / 256), 256, 0, stream>>>(hx, row, col, dinv, h);
    }
    k_bias_relu<<<(n * D_H + 255) / 256, 256, 0, stream>>>(h, b1, n);

    k_gemm2<<<(n + G2_NODES - 1) / G2_NODES, 256, 0, stream>>>(h, W2, hx2, n);

    k_self2<<<(n * D_OUT + 255) / 256, 256, 0, stream>>>(hx2, dinv, out, n);
    {
        long long total = (long long)e * D_OUT;
        k_edge2<<<(int)((total + 255) / 256), 256, 0, stream>>>(hx2, row, col, dinv, out);
    }
    k_lsm<<<(n + 255) / 256, 256, 0, stream>>>(out, b2, n);
}

// Round 2
// 722.530 us; speedup vs baseline: 1.8342x; 1.8342x over previous
//
#include <hip/hip_runtime.h>
#include <math.h>

#define N_NODES 100000
#define N_EDGES 1600000
#define D_IN 256
#define D_H 128
#define D_OUT 32
#define N_PAD 102400  // padded node count for int arrays

typedef long long ll;

// ---------------- degree histogram ----------------
__global__ void k_count(const int* __restrict__ col, int* __restrict__ deg, int e) {
    int i = blockIdx.x * blockDim.x + threadIdx.x;
    if (i < e) atomicAdd(&deg[col[i]], 1);
}

// ---------------- exclusive scan (3 kernels) ----------------
__global__ void k_scan1(const int* __restrict__ deg, int* __restrict__ rp,
                        int* __restrict__ bsum, int n) {
    __shared__ int s[256];
    int i = blockIdx.x * 256 + threadIdx.x;
    int v = (i < n) ? deg[i] : 0;
    s[threadIdx.x] = v;
    __syncthreads();
    for (int off = 1; off < 256; off <<= 1) {
        int t = (threadIdx.x >= off) ? s[threadIdx.x - off] : 0;
        __syncthreads();
        s[threadIdx.x] += t;
        __syncthreads();
    }
    if (i < n) rp[i] = s[threadIdx.x] - v;  // exclusive within block
    if (threadIdx.x == 255) bsum[blockIdx.x] = s[255];
}

__global__ void k_scan2(int* __restrict__ bsum, int nb) {
    __shared__ int s[512];
    int v = (threadIdx.x < nb) ? bsum[threadIdx.x] : 0;
    s[threadIdx.x] = v;
    __syncthreads();
    for (int off = 1; off < 512; off <<= 1) {
        int t = (threadIdx.x >= off) ? s[threadIdx.x - off] : 0;
        __syncthreads();
        s[threadIdx.x] += t;
        __syncthreads();
    }
    if (threadIdx.x < nb) bsum[threadIdx.x] = s[threadIdx.x] - v;  // exclusive
}

// add block offsets + compute dinv = rsqrt(1+deg)
__global__ void k_finalize(int* __restrict__ rp, const int* __restrict__ bsum,
                           const int* __restrict__ deg, float* __restrict__ dinv, int n) {
    int i = blockIdx.x * 256 + threadIdx.x;
    if (i < n) {
        rp[i] += bsum[i >> 8];
        dinv[i] = rsqrtf((float)(1 + deg[i]));
    }
}

// ---------------- CSR fill (sorted by target) ----------------
__global__ void k_fill(const int* __restrict__ row, const int* __restrict__ col,
                       const int* __restrict__ rp, int* __restrict__ cursor,
                       int* __restrict__ csr_src, int e) {
    int i = blockIdx.x * blockDim.x + threadIdx.x;
    if (i < e) {
        int c = col[i];
        int pos = rp[c] + atomicAdd(&cursor[c], 1);
        csr_src[pos] = row[i];
    }
}

// ---------------- GEMM1: hxs = dinv * (x @ W1) ----------------
#define G1_NODES 8
__global__ __launch_bounds__(128) void k_gemm1(const float* __restrict__ x,
                                               const float* __restrict__ W,
                                               const float* __restrict__ dinv,
                                               float* __restrict__ hxs, int n) {
    __shared__ float xs[G1_NODES][D_IN];
    const int tid = threadIdx.x;  // 0..127
    const int base = blockIdx.x * G1_NODES;
    for (int i = tid; i < G1_NODES * D_IN; i += 128) {
        int r = i >> 8, c = i & 255;
        int node = base + r;
        xs[r][c] = (node < n) ? x[(ll)node * D_IN + c] : 0.0f;
    }
    __syncthreads();
    float acc[G1_NODES];
#pragma unroll
    for (int j = 0; j < G1_NODES; j++) acc[j] = 0.0f;
    for (int k = 0; k < D_IN; k++) {
        float w = W[k * D_H + tid];
#pragma unroll
        for (int j = 0; j < G1_NODES; j++) acc[j] += xs[j][k] * w;
    }
#pragma unroll
    for (int j = 0; j < G1_NODES; j++) {
        int node = base + j;
        if (node < n) hxs[(ll)node * D_H + tid] = acc[j] * dinv[node];
    }
}

// ---------------- layer-1 gather aggregation + bias + relu ----------------
// h[v] = relu(dinv[v] * (hxs[v] + sum_{r->v} hxs[r]) + b1)
__global__ __launch_bounds__(256) void k_agg1(const float* __restrict__ hxs,
                                              const int* __restrict__ csr_src,
                                              const int* __restrict__ rp,
                                              const int* __restrict__ deg,
                                              const float* __restrict__ dinv,
                                              const float* __restrict__ b1,
                                              float* __restrict__ h, int n) {
    int v = blockIdx.x * 2 + (threadIdx.x >> 7);
    if (v >= n) return;
    int d = threadIdx.x & 127;
    float acc = hxs[(ll)v * D_H + d];
    int s = rp[v], e = s + deg[v];
    int i = s;
    for (; i + 1 < e; i += 2) {
        int s0 = csr_src[i], s1 = csr_src[i + 1];
        float a0 = hxs[(ll)s0 * D_H + d];
        float a1 = hxs[(ll)s1 * D_H + d];
        acc += a0 + a1;
    }
    if (i < e) acc += hxs[(ll)csr_src[i] * D_H + d];
    h[(ll)v * D_H + d] = fmaxf(fmaf(dinv[v], acc, b1[d]), 0.0f);
}

// ---------------- GEMM2: hx2s = dinv * (h @ W2) ----------------
#define G2_NODES 8
__global__ __launch_bounds__(256) void k_gemm2(const float* __restrict__ h,
                                               const float* __restrict__ W,
                                               const float* __restrict__ dinv,
                                               float* __restrict__ hx2s, int n) {
    __shared__ float Ws[D_H * D_OUT];    // 16 KB
    __shared__ float hs[G2_NODES][D_H];  // 4 KB
    const int tid = threadIdx.x;         // 0..255
    const int base = blockIdx.x * G2_NODES;
    for (int i = tid; i < D_H * D_OUT; i += 256) Ws[i] = W[i];
    for (int i = tid; i < G2_NODES * D_H; i += 256) {
        int r = i >> 7, c = i & 127;
        int node = base + r;
        hs[r][c] = (node < n) ? h[(ll)node * D_H + c] : 0.0f;
    }
    __syncthreads();
    int r = tid >> 5, d = tid & 31;
    int node = base + r;
    float acc = 0.0f;
#pragma unroll 8
    for (int k = 0; k < D_H; k++) acc += hs[r][k] * Ws[k * D_OUT + d];
    if (node < n) hx2s[(ll)node * D_OUT + d] = acc * dinv[node];
}

// ---------------- layer-2 gather aggregation + bias + log_softmax ----------------
__global__ __launch_bounds__(256) void k_agg2(const float* __restrict__ hx2s,
                                              const int* __restrict__ csr_src,
                                              const int* __restrict__ rp,
                                              const int* __restrict__ deg,
                                              const float* __restrict__ dinv,
                                              const float* __restrict__ b2,
                                              float* __restrict__ out, int n) {
    int v = blockIdx.x * 8 + (threadIdx.x >> 5);
    if (v >= n) return;
    int d = threadIdx.x & 31;
    float acc = hx2s[(ll)v * D_OUT + d];
    int s = rp[v], e = s + deg[v];
    int i = s;
    for (; i + 1 < e; i += 2) {
        int s0 = csr_src[i], s1 = csr_src[i + 1];
        float a0 = hx2s[(ll)s0 * D_OUT + d];
        float a1 = hx2s[(ll)s1 * D_OUT + d];
        acc += a0 + a1;
    }
    if (i < e) acc += hx2s[(ll)csr_src[i] * D_OUT + d];
    float t = fmaf(dinv[v], acc, b2[d]);
    // log-softmax over 32 lanes (xor masks <=16 stay within each 32-lane half of the wave)
    float mx = t;
#pragma unroll
    for (int m = 16; m >= 1; m >>= 1) mx = fmaxf(mx, __shfl_xor(mx, m));
    float ex = __expf(t - mx);
    float sum = ex;
#pragma unroll
    for (int m = 16; m >= 1; m >>= 1) sum += __shfl_xor(sum, m);
    out[(ll)v * D_OUT + d] = t - mx - __logf(sum);
}

extern "C" void kernel_launch(void* const* d_in, const int* in_sizes, int n_in,
                              void* d_out, int out_size, void* d_ws, size_t ws_size,
                              hipStream_t stream) {
    const float* x  = (const float*)d_in[0];
    const float* W1 = (const float*)d_in[1];
    const float* b1 = (const float*)d_in[2];
    const float* W2 = (const float*)d_in[3];
    const float* b2 = (const float*)d_in[4];
    const int*   ei = (const int*)d_in[5];
    const int* row = ei;            // sources
    const int* col = ei + N_EDGES;  // targets
    float* out = (float*)d_out;

    // workspace layout (4-byte units):
    // deg[N_PAD] | rp[N_PAD] | cursor[N_PAD] | bsum[512] | dinv[N_PAD] | csr_src[E] | hxs[N*128] | h[N*128]
    // hx2s aliases hxs (dead after k_agg1).  Total ~110 MB.
    int*   ws_i    = (int*)d_ws;
    int*   deg     = ws_i;
    int*   rp      = ws_i + N_PAD;
    int*   cursor  = ws_i + 2 * N_PAD;
    int*   bsum    = ws_i + 3 * N_PAD;
    float* dinv    = (float*)(ws_i + 3 * N_PAD + 512);
    int*   csr_src = ws_i + 4 * N_PAD + 512;
    float* hxs     = (float*)(csr_src + N_EDGES);
    float* h       = hxs + (ll)N_NODES * D_H;
    float* hx2s    = hxs;  // alias

    const int n = N_NODES, e = N_EDGES;
    const int nb = (n + 255) / 256;  // 391 scan blocks

    // zero deg + cursor (one memset covers deg|rp|cursor; rp overwritten by scan)
    hipMemsetAsync(deg, 0, 3 * N_PAD * sizeof(int), stream);

    k_count<<<(e + 255) / 256, 256, 0, stream>>>(col, deg, e);
    k_scan1<<<nb, 256, 0, stream>>>(deg, rp, bsum, n);
    k_scan2<<<1, 512, 0, stream>>>(bsum, nb);
    k_finalize<<<nb, 256, 0, stream>>>(rp, bsum, deg, dinv, n);
    k_fill<<<(e + 255) / 256, 256, 0, stream>>>(row, col, rp, cursor, csr_src, e);

    k_gemm1<<<(n + G1_NODES - 1) / G1_NODES, 128, 0, stream>>>(x, W1, dinv, hxs, n);
    k_agg1<<<(n + 1) / 2, 256, 0, stream>>>(hxs, csr_src, rp, deg, dinv, b1, h, n);
    k_gemm2<<<(n + G2_NODES - 1) / G2_NODES, 256, 0, stream>>>(h, W2, dinv, hx2s, n);
    k_agg2<<<(n + 7) / 8, 256, 0, stream>>>(hx2s, csr_src, rp, deg, dinv, b2, out, n);
}

// Round 3
// 467.827 us; speedup vs baseline: 2.8328x; 1.5444x over previous
//
#include <hip/hip_runtime.h>
#include <math.h>

#define N_NODES 100000
#define N_EDGES 1600000
#define D_IN 256
#define D_H 128
#define D_OUT 32
#define N_PAD 102400

typedef long long ll;
typedef unsigned int uint;
typedef unsigned short ushort;
typedef short frag_ab __attribute__((ext_vector_type(8)));   // 8 bf16
typedef float frag_cd __attribute__((ext_vector_type(4)));   // 4 f32

__device__ __forceinline__ ushort f2bf(float f) {            // RNE fp32->bf16
    uint u = __float_as_uint(f);
    u += 0x7FFFu + ((u >> 16) & 1u);
    return (ushort)(u >> 16);
}
__device__ __forceinline__ float bfl(uint u) { return __uint_as_float(u << 16); }
__device__ __forceinline__ float bfh(uint u) { return __uint_as_float(u & 0xFFFF0000u); }

// ---------------- degree histogram ----------------
__global__ void k_count(const int* __restrict__ col, int* __restrict__ deg, int e) {
    int i = blockIdx.x * blockDim.x + threadIdx.x;
    if (i < e) atomicAdd(&deg[col[i]], 1);
}

// ---------------- exclusive scan ----------------
__global__ void k_scan1(const int* __restrict__ deg, int* __restrict__ rp,
                        int* __restrict__ bsum, int n) {
    __shared__ int s[256];
    int i = blockIdx.x * 256 + threadIdx.x;
    int v = (i < n) ? deg[i] : 0;
    s[threadIdx.x] = v;
    __syncthreads();
    for (int off = 1; off < 256; off <<= 1) {
        int t = (threadIdx.x >= off) ? s[threadIdx.x - off] : 0;
        __syncthreads();
        s[threadIdx.x] += t;
        __syncthreads();
    }
    if (i < n) rp[i] = s[threadIdx.x] - v;
    if (threadIdx.x == 255) bsum[blockIdx.x] = s[255];
}

__global__ void k_scan2(int* __restrict__ bsum, int nb) {
    __shared__ int s[512];
    int v = (threadIdx.x < nb) ? bsum[threadIdx.x] : 0;
    s[threadIdx.x] = v;
    __syncthreads();
    for (int off = 1; off < 512; off <<= 1) {
        int t = (threadIdx.x >= off) ? s[threadIdx.x - off] : 0;
        __syncthreads();
        s[threadIdx.x] += t;
        __syncthreads();
    }
    if (threadIdx.x < nb) bsum[threadIdx.x] = s[threadIdx.x] - v;
}

__global__ void k_finalize(int* __restrict__ rp, const int* __restrict__ bsum,
                           const int* __restrict__ deg, float* __restrict__ dinv, int n) {
    int i = blockIdx.x * 256 + threadIdx.x;
    if (i < n) {
        rp[i] += bsum[i >> 8];
        dinv[i] = rsqrtf((float)(1 + deg[i]));
    }
}

// ---------------- CSR fill ----------------
__global__ void k_fill(const int* __restrict__ row, const int* __restrict__ col,
                       const int* __restrict__ rp, int* __restrict__ cursor,
                       int* __restrict__ csr_src, int e) {
    int i = blockIdx.x * blockDim.x + threadIdx.x;
    if (i < e) {
        int c = col[i];
        int pos = rp[c] + atomicAdd(&cursor[c], 1);
        csr_src[pos] = row[i];
    }
}

// ---------------- weight transpose+convert: w1t[n][k], w2t[n][k] bf16 ----------------
__global__ void k_prep_w(const float* __restrict__ W1, const float* __restrict__ W2,
                         ushort* __restrict__ w1t, ushort* __restrict__ w2t) {
    int i = blockIdx.x * 256 + threadIdx.x;
    if (i < D_IN * D_H) {                     // 32768
        int k = i >> 7, nn = i & 127;
        w1t[nn * D_IN + k] = f2bf(W1[i]);
    } else if (i < D_IN * D_H + D_H * D_OUT) { // + 4096
        int j = i - D_IN * D_H;
        int k = j >> 5, nn = j & 31;
        w2t[nn * D_H + k] = f2bf(W2[j]);
    }
}

// ---------------- GEMM1 (MFMA): hxs = bf16( dinv * (x @ W1) ) ----------------
// block: 128 nodes x 128 dims, K=256 in 4 chunks of 64. 4 waves, wave w -> dims [32w,32w+32)
__global__ __launch_bounds__(256) void k_gemm1(const float* __restrict__ x,
                                               const ushort* __restrict__ w1t,
                                               const float* __restrict__ dinv,
                                               ushort* __restrict__ hxs, int n) {
    __shared__ ushort xs[128 * 72];  // [node][64k + 8 pad]
    __shared__ ushort ws[128 * 72];  // [dim][64k + 8 pad]
    const int tid = threadIdx.x;
    const int w = tid >> 6, lane = tid & 63;
    const int lm = lane & 15, quad = lane >> 4;
    const int base = blockIdx.x * 128;

    frag_cd acc[8][2];
#pragma unroll
    for (int mt = 0; mt < 8; mt++)
#pragma unroll
        for (int nt = 0; nt < 2; nt++) acc[mt][nt] = (frag_cd){0.f, 0.f, 0.f, 0.f};

    for (int kc = 0; kc < 4; kc++) {
#pragma unroll
        for (int t = 0; t < 8; t++) {          // stage x chunk (fp32 -> bf16)
            int f = tid + 256 * t;             // 0..2047
            int node = f >> 4, k4 = f & 15;
            int gn = base + node;
            float4 v4 = (gn < n) ? ((const float4*)x)[(ll)gn * 64 + kc * 16 + k4]
                                 : make_float4(0.f, 0.f, 0.f, 0.f);
            uint p0 = (uint)f2bf(v4.x) | ((uint)f2bf(v4.y) << 16);
            uint p1 = (uint)f2bf(v4.z) | ((uint)f2bf(v4.w) << 16);
            *(uint2*)&xs[node * 72 + k4 * 4] = make_uint2(p0, p1);
        }
#pragma unroll
        for (int t = 0; t < 4; t++) {          // stage w1t chunk
            int f = tid + 256 * t;             // 0..1023
            int nn = f >> 3, k8 = f & 7;
            uint4 v = *(const uint4*)&w1t[nn * 256 + kc * 64 + k8 * 8];
            *(uint4*)&ws[nn * 72 + k8 * 8] = v;
        }
        __syncthreads();
#pragma unroll
        for (int ks = 0; ks < 2; ks++) {
            int ko = ks * 32 + quad * 8;
            frag_ab a[8], b[2];
#pragma unroll
            for (int mt = 0; mt < 8; mt++)
                a[mt] = *(const frag_ab*)&xs[(mt * 16 + lm) * 72 + ko];
#pragma unroll
            for (int nt = 0; nt < 2; nt++)
                b[nt] = *(const frag_ab*)&ws[(w * 32 + nt * 16 + lm) * 72 + ko];
#pragma unroll
            for (int mt = 0; mt < 8; mt++)
#pragma unroll
                for (int nt = 0; nt < 2; nt++)
                    acc[mt][nt] = __builtin_amdgcn_mfma_f32_16x16x32_bf16(
                        a[mt], b[nt], acc[mt][nt], 0, 0, 0);
        }
        __syncthreads();
    }
#pragma unroll
    for (int mt = 0; mt < 8; mt++) {
#pragma unroll
        for (int r = 0; r < 4; r++) {
            int node = base + mt * 16 + quad * 4 + r;
            if (node < n) {
                float dv = dinv[node];
#pragma unroll
                for (int nt = 0; nt < 2; nt++) {
                    int dim = w * 32 + nt * 16 + lm;
                    hxs[(ll)node * D_H + dim] = f2bf(acc[mt][nt][r] * dv);
                }
            }
        }
    }
}

// ---------------- layer-1 gather (bf16 rows): one wave per node ----------------
__global__ __launch_bounds__(256) void k_agg1(const uint* __restrict__ hxs,
                                              const int* __restrict__ csr_src,
                                              const int* __restrict__ rp,
                                              const int* __restrict__ deg,
                                              const float* __restrict__ dinv,
                                              const float* __restrict__ b1,
                                              uint* __restrict__ h, int n) {
    int v = blockIdx.x * 4 + (threadIdx.x >> 6);
    if (v >= n) return;
    int lane = threadIdx.x & 63;
    uint u = hxs[v * 64 + lane];
    float a0 = bfl(u), a1 = bfh(u);
    int s = rp[v], e = s + deg[v];
    int i = s;
    for (; i + 3 < e; i += 4) {
        int s0 = csr_src[i], s1 = csr_src[i + 1];
        int s2 = csr_src[i + 2], s3 = csr_src[i + 3];
        uint u0 = hxs[s0 * 64 + lane], u1 = hxs[s1 * 64 + lane];
        uint u2 = hxs[s2 * 64 + lane], u3 = hxs[s3 * 64 + lane];
        a0 += bfl(u0) + bfl(u1) + bfl(u2) + bfl(u3);
        a1 += bfh(u0) + bfh(u1) + bfh(u2) + bfh(u3);
    }
    for (; i < e; i++) {
        uint u0 = hxs[csr_src[i] * 64 + lane];
        a0 += bfl(u0);
        a1 += bfh(u0);
    }
    float dv = dinv[v];
    float2 bb = ((const float2*)b1)[lane];
    float h0 = fmaxf(fmaf(dv, a0, bb.x), 0.f);
    float h1 = fmaxf(fmaf(dv, a1, bb.y), 0.f);
    h[v * 64 + lane] = (uint)f2bf(h0) | ((uint)f2bf(h1) << 16);
}

// ---------------- GEMM2 (MFMA): hx2s = bf16( dinv * (h @ W2) ) ----------------
// block: 128 nodes x 32 dims, K=128 single stage. wave w -> nodes [32w,32w+32)
__global__ __launch_bounds__(256) void k_gemm2(const ushort* __restrict__ h,
                                               const ushort* __restrict__ w2t,
                                               const float* __restrict__ dinv,
                                               ushort* __restrict__ hx2s, int n) {
    __shared__ ushort hs[128 * 136];  // [node][128k + 8 pad]
    __shared__ ushort ws[32 * 136];
    const int tid = threadIdx.x;
    const int w = tid >> 6, lane = tid & 63;
    const int lm = lane & 15, quad = lane >> 4;
    const int base = blockIdx.x * 128;

#pragma unroll
    for (int t = 0; t < 8; t++) {      // stage h
        int f = tid + 256 * t;         // 0..2047
        int node = f >> 4, k8 = f & 15;
        int gn = base + node;
        uint4 v = (gn < n) ? *(const uint4*)&h[(ll)gn * 128 + k8 * 8]
                           : make_uint4(0u, 0u, 0u, 0u);
        *(uint4*)&hs[node * 136 + k8 * 8] = v;
    }
#pragma unroll
    for (int t = 0; t < 2; t++) {      // stage w2t
        int f = tid + 256 * t;         // 0..511
        int nn = f >> 4, k8 = f & 15;
        uint4 v = *(const uint4*)&w2t[nn * 128 + k8 * 8];
        *(uint4*)&ws[nn * 136 + k8 * 8] = v;
    }
    __syncthreads();

    frag_cd acc[2][2];
#pragma unroll
    for (int mt = 0; mt < 2; mt++)
#pragma unroll
        for (int nt = 0; nt < 2; nt++) acc[mt][nt] = (frag_cd){0.f, 0.f, 0.f, 0.f};

#pragma unroll
    for (int ks = 0; ks < 4; ks++) {
        int ko = ks * 32 + quad * 8;
        frag_ab a[2], b[2];
#pragma unroll
        for (int mt = 0; mt < 2; mt++)
            a[mt] = *(const frag_ab*)&hs[(w * 32 + mt * 16 + lm) * 136 + ko];
#pragma unroll
        for (int nt = 0; nt < 2; nt++)
            b[nt] = *(const frag_ab*)&ws[(nt * 16 + lm) * 136 + ko];
#pragma unroll
        for (int mt = 0; mt < 2; mt++)
#pragma unroll
            for (int nt = 0; nt < 2; nt++)
                acc[mt][nt] = __builtin_amdgcn_mfma_f32_16x16x32_bf16(
                    a[mt], b[nt], acc[mt][nt], 0, 0, 0);
    }
#pragma unroll
    for (int mt = 0; mt < 2; mt++) {
#pragma unroll
        for (int r = 0; r < 4; r++) {
            int node = base + w * 32 + mt * 16 + quad * 4 + r;
            if (node < n) {
                float dv = dinv[node];
#pragma unroll
                for (int nt = 0; nt < 2; nt++) {
                    int dim = nt * 16 + lm;
                    hx2s[(ll)node * D_OUT + dim] = f2bf(acc[mt][nt][r] * dv);
                }
            }
        }
    }
}

// ---------------- layer-2 gather + bias + log_softmax: 16 lanes per node ----------------
__global__ __launch_bounds__(256) void k_agg2(const uint* __restrict__ hx2s,
                                              const int* __restrict__ csr_src,
                                              const int* __restrict__ rp,
                                              const int* __restrict__ deg,
                                              const float* __restrict__ dinv,
                                              const float* __restrict__ b2,
                                              float2* __restrict__ out, int n) {
    int v = blockIdx.x * 16 + (threadIdx.x >> 4);
    if (v >= n) return;
    int l16 = threadIdx.x & 15;
    uint u = hx2s[v * 16 + l16];
    float a0 = bfl(u), a1 = bfh(u);
    int s = rp[v], e = s + deg[v];
    int i = s;
    for (; i + 3 < e; i += 4) {
        int s0 = csr_src[i], s1 = csr_src[i + 1];
        int s2 = csr_src[i + 2], s3 = csr_src[i + 3];
        uint u0 = hx2s[s0 * 16 + l16], u1 = hx2s[s1 * 16 + l16];
        uint u2 = hx2s[s2 * 16 + l16], u3 = hx2s[s3 * 16 + l16];
        a0 += bfl(u0) + bfl(u1) + bfl(u2) + bfl(u3);
        a1 += bfh(u0) + bfh(u1) + bfh(u2) + bfh(u3);
    }
    for (; i < e; i++) {
        uint u0 = hx2s[csr_src[i] * 16 + l16];
        a0 += bfl(u0);
        a1 += bfh(u0);
    }
    float dv = dinv[v];
    float2 bb = ((const float2*)b2)[l16];
    float t0 = fmaf(dv, a0, bb.x), t1 = fmaf(dv, a1, bb.y);
    float mx = fmaxf(t0, t1);
#pragma unroll
    for (int m = 8; m >= 1; m >>= 1) mx = fmaxf(mx, __shfl_xor(mx, m));
    float sum = __expf(t0 - mx) + __expf(t1 - mx);
#pragma unroll
    for (int m = 8; m >= 1; m >>= 1) sum += __shfl_xor(sum, m);
    float lse = mx + __logf(sum);
    out[v * 16 + l16] = make_float2(t0 - lse, t1 - lse);
}

extern "C" void kernel_launch(void* const* d_in, const int* in_sizes, int n_in,
                              void* d_out, int out_size, void* d_ws, size_t ws_size,
                              hipStream_t stream) {
    const float* x  = (const float*)d_in[0];
    const float* W1 = (const float*)d_in[1];
    const float* b1 = (const float*)d_in[2];
    const float* W2 = (const float*)d_in[3];
    const float* b2 = (const float*)d_in[4];
    const int*   ei = (const int*)d_in[5];
    const int* row = ei;
    const int* col = ei + N_EDGES;
    float* out = (float*)d_out;

    // ws layout (4B words): deg|rp|cursor [N_PAD each] | bsum[512] | dinv[N_PAD] |
    //   csr_src[E] | w1t(bf16 32768) | w2t(bf16 4096) | hxs(bf16 N*128) | h(bf16 N*128) | hx2s(bf16 N*32)
    int*   ws_i    = (int*)d_ws;
    int*   deg     = ws_i;
    int*   rp      = ws_i + N_PAD;
    int*   cursor  = ws_i + 2 * N_PAD;
    int*   bsum    = ws_i + 3 * N_PAD;
    float* dinv    = (float*)(ws_i + 3 * N_PAD + 512);
    int*   csr_src = ws_i + 4 * N_PAD + 512;
    ushort* w1t    = (ushort*)(csr_src + N_EDGES);
    ushort* w2t    = w1t + D_IN * D_H;
    ushort* hxs    = w2t + D_H * D_OUT;
    ushort* h      = hxs + (ll)N_NODES * D_H;
    ushort* hx2s   = h + (ll)N_NODES * D_H;

    const int n = N_NODES, e = N_EDGES;
    const int nb = (n + 255) / 256;

    hipMemsetAsync(deg, 0, 3 * N_PAD * sizeof(int), stream);

    k_count<<<(e + 255) / 256, 256, 0, stream>>>(col, deg, e);
    k_scan1<<<nb, 256, 0, stream>>>(deg, rp, bsum, n);
    k_scan2<<<1, 512, 0, stream>>>(bsum, nb);
    k_finalize<<<nb, 256, 0, stream>>>(rp, bsum, deg, dinv, n);
    k_fill<<<(e + 255) / 256, 256, 0, stream>>>(row, col, rp, cursor, csr_src, e);
    k_prep_w<<<(D_IN * D_H + D_H * D_OUT + 255) / 256, 256, 0, stream>>>(W1, W2, w1t, w2t);

    k_gemm1<<<(n + 127) / 128, 256, 0, stream>>>(x, w1t, dinv, hxs, n);
    k_agg1<<<(n + 3) / 4, 256, 0, stream>>>((const uint*)hxs, csr_src, rp, deg, dinv, b1,
                                            (uint*)h, n);
    k_gemm2<<<(n + 127) / 128, 256, 0, stream>>>(h, w2t, dinv, hx2s, n);
    k_agg2<<<(n + 15) / 16, 256, 0, stream>>>((const uint*)hx2s, csr_src, rp, deg, dinv, b2,
                                              (float2*)out, n);
}

// Round 4
// 437.071 us; speedup vs baseline: 3.0321x; 1.0704x over previous
//
#include <hip/hip_runtime.h>
#include <math.h>

#define N_NODES 100000
#define N_EDGES 1600000
#define D_IN 256
#define D_H 128
#define D_OUT 32
#define N_PAD 102400
#define NB 196      // ceil(N_NODES / 512) buckets of 512 nodes
#define CHUNK 4096  // edges per pass-A block

typedef long long ll;
typedef unsigned int uint;
typedef unsigned short ushort;
typedef short frag_ab __attribute__((ext_vector_type(8)));   // 8 bf16
typedef float frag_cd __attribute__((ext_vector_type(4)));   // 4 f32

__device__ __forceinline__ ushort f2bf(float f) {            // RNE fp32->bf16
    uint u = __float_as_uint(f);
    u += 0x7FFFu + ((u >> 16) & 1u);
    return (ushort)(u >> 16);
}
__device__ __forceinline__ float bfl(uint u) { return __uint_as_float(u << 16); }
__device__ __forceinline__ float bfh(uint u) { return __uint_as_float(u & 0xFFFF0000u); }

// ---------------- degree histogram ----------------
__global__ void k_count(const int* __restrict__ col, int* __restrict__ deg, int e) {
    int i = blockIdx.x * blockDim.x + threadIdx.x;
    if (i < e) atomicAdd(&deg[col[i]], 1);
}

// ---------------- exclusive scan ----------------
__global__ void k_scan1(const int* __restrict__ deg, int* __restrict__ rp,
                        int* __restrict__ bsum, int n) {
    __shared__ int s[256];
    int i = blockIdx.x * 256 + threadIdx.x;
    int v = (i < n) ? deg[i] : 0;
    s[threadIdx.x] = v;
    __syncthreads();
    for (int off = 1; off < 256; off <<= 1) {
        int t = (threadIdx.x >= off) ? s[threadIdx.x - off] : 0;
        __syncthreads();
        s[threadIdx.x] += t;
        __syncthreads();
    }
    if (i < n) rp[i] = s[threadIdx.x] - v;
    if (threadIdx.x == 255) bsum[blockIdx.x] = s[255];
}

__global__ void k_scan2(int* __restrict__ bsum, int nb) {
    __shared__ int s[512];
    int v = (threadIdx.x < nb) ? bsum[threadIdx.x] : 0;
    s[threadIdx.x] = v;
    __syncthreads();
    for (int off = 1; off < 512; off <<= 1) {
        int t = (threadIdx.x >= off) ? s[threadIdx.x - off] : 0;
        __syncthreads();
        s[threadIdx.x] += t;
        __syncthreads();
    }
    if (threadIdx.x < nb) bsum[threadIdx.x] = s[threadIdx.x] - v;
}

__global__ void k_finalize(int* __restrict__ rp, const int* __restrict__ bsum,
                           const int* __restrict__ deg, float* __restrict__ dinv, int n) {
    int i = blockIdx.x * 256 + threadIdx.x;
    if (i < n) {
        rp[i] += bsum[i >> 8];
        dinv[i] = rsqrtf((float)(1 + deg[i]));
    }
}

// gcur[b] = start of bucket b's region in the CSR / pair arrays
__global__ void k_initcur(const int* __restrict__ rp, int* __restrict__ gcur) {
    int t = threadIdx.x;
    if (t < NB) gcur[t] = rp[t << 9];
}

// ---------------- pass A: bucket partition (packed row<<9 | local-node) ----------------
__global__ __launch_bounds__(256) void k_bucketA(const int* __restrict__ row,
                                                 const int* __restrict__ col,
                                                 int* __restrict__ gcur,
                                                 uint* __restrict__ pairs, int e) {
    __shared__ int cnt[NB];
    __shared__ int lstart[NB];
    const int t = threadIdx.x;
    for (int i = t; i < NB; i += 256) cnt[i] = 0;
    __syncthreads();
    const int base = blockIdx.x * CHUNK;
    int myc[CHUNK / 256];
#pragma unroll
    for (int j = 0; j < CHUNK / 256; j++) {
        int idx = base + t + j * 256;
        int c = (idx < e) ? col[idx] : -1;
        myc[j] = c;
        if (c >= 0) atomicAdd(&cnt[c >> 9], 1);
    }
    __syncthreads();
    for (int i = t; i < NB; i += 256) {
        int c = cnt[i];
        lstart[i] = (c > 0) ? atomicAdd(&gcur[i], c) : 0;
        cnt[i] = 0;  // reuse as local cursor
    }
    __syncthreads();
#pragma unroll
    for (int j = 0; j < CHUNK / 256; j++) {
        int c = myc[j];
        if (c >= 0) {
            int idx = base + t + j * 256;
            int b = c >> 9;
            int pos = lstart[b] + atomicAdd(&cnt[b], 1);
            pairs[pos] = ((uint)row[idx] << 9) | (uint)(c & 511);
        }
    }
}

// ---------------- pass B: per-bucket exact CSR fill (single-CU regions) ----------------
__global__ __launch_bounds__(256) void k_bucketB(const uint* __restrict__ pairs,
                                                 const int* __restrict__ rp,
                                                 int* __restrict__ csr_src, int e, int n) {
    __shared__ int cur[512];
    const int b = blockIdx.x;
    const int node0 = b << 9;
    const int nn = min(512, n - node0);
    const int t = threadIdx.x;
    for (int i = t; i < nn; i += 256) cur[i] = rp[node0 + i];
    __syncthreads();
    const int pb = rp[node0];
    const int pe = (node0 + 512 < n) ? rp[node0 + 512] : e;
    for (int i = pb + t; i < pe; i += 256) {
        uint p = pairs[i];
        int pos = atomicAdd(&cur[p & 511], 1);
        csr_src[pos] = (int)(p >> 9);
    }
}

// ---------------- weight transpose+convert: w1t[n][k], w2t[n][k] bf16 ----------------
__global__ void k_prep_w(const float* __restrict__ W1, const float* __restrict__ W2,
                         ushort* __restrict__ w1t, ushort* __restrict__ w2t) {
    int i = blockIdx.x * 256 + threadIdx.x;
    if (i < D_IN * D_H) {
        int k = i >> 7, nn = i & 127;
        w1t[nn * D_IN + k] = f2bf(W1[i]);
    } else if (i < D_IN * D_H + D_H * D_OUT) {
        int j = i - D_IN * D_H;
        int k = j >> 5, nn = j & 31;
        w2t[nn * D_H + k] = f2bf(W2[j]);
    }
}

// ---------------- GEMM1 (MFMA): hxs = bf16( dinv * (x @ W1) ) ----------------
__global__ __launch_bounds__(256) void k_gemm1(const float* __restrict__ x,
                                               const ushort* __restrict__ w1t,
                                               const float* __restrict__ dinv,
                                               ushort* __restrict__ hxs, int n) {
    __shared__ ushort xs[128 * 72];
    __shared__ ushort ws[128 * 72];
    const int tid = threadIdx.x;
    const int w = tid >> 6, lane = tid & 63;
    const int lm = lane & 15, quad = lane >> 4;
    const int base = blockIdx.x * 128;

    frag_cd acc[8][2];
#pragma unroll
    for (int mt = 0; mt < 8; mt++)
#pragma unroll
        for (int nt = 0; nt < 2; nt++) acc[mt][nt] = (frag_cd){0.f, 0.f, 0.f, 0.f};

    for (int kc = 0; kc < 4; kc++) {
#pragma unroll
        for (int t = 0; t < 8; t++) {
            int f = tid + 256 * t;
            int node = f >> 4, k4 = f & 15;
            int gn = base + node;
            float4 v4 = (gn < n) ? ((const float4*)x)[(ll)gn * 64 + kc * 16 + k4]
                                 : make_float4(0.f, 0.f, 0.f, 0.f);
            uint p0 = (uint)f2bf(v4.x) | ((uint)f2bf(v4.y) << 16);
            uint p1 = (uint)f2bf(v4.z) | ((uint)f2bf(v4.w) << 16);
            *(uint2*)&xs[node * 72 + k4 * 4] = make_uint2(p0, p1);
        }
#pragma unroll
        for (int t = 0; t < 4; t++) {
            int f = tid + 256 * t;
            int nn = f >> 3, k8 = f & 7;
            uint4 v = *(const uint4*)&w1t[nn * 256 + kc * 64 + k8 * 8];
            *(uint4*)&ws[nn * 72 + k8 * 8] = v;
        }
        __syncthreads();
#pragma unroll
        for (int ks = 0; ks < 2; ks++) {
            int ko = ks * 32 + quad * 8;
            frag_ab a[8], b[2];
#pragma unroll
            for (int mt = 0; mt < 8; mt++)
                a[mt] = *(const frag_ab*)&xs[(mt * 16 + lm) * 72 + ko];
#pragma unroll
            for (int nt = 0; nt < 2; nt++)
                b[nt] = *(const frag_ab*)&ws[(w * 32 + nt * 16 + lm) * 72 + ko];
#pragma unroll
            for (int mt = 0; mt < 8; mt++)
#pragma unroll
                for (int nt = 0; nt < 2; nt++)
                    acc[mt][nt] = __builtin_amdgcn_mfma_f32_16x16x32_bf16(
                        a[mt], b[nt], acc[mt][nt], 0, 0, 0);
        }
        __syncthreads();
    }
#pragma unroll
    for (int mt = 0; mt < 8; mt++) {
#pragma unroll
        for (int r = 0; r < 4; r++) {
            int node = base + mt * 16 + quad * 4 + r;
            if (node < n) {
                float dv = dinv[node];
#pragma unroll
                for (int nt = 0; nt < 2; nt++) {
                    int dim = w * 32 + nt * 16 + lm;
                    hxs[(ll)node * D_H + dim] = f2bf(acc[mt][nt][r] * dv);
                }
            }
        }
    }
}

// ---------------- layer-1 gather (bf16 rows): one wave per node ----------------
__global__ __launch_bounds__(256) void k_agg1(const uint* __restrict__ hxs,
                                              const int* __restrict__ csr_src,
                                              const int* __restrict__ rp,
                                              const int* __restrict__ deg,
                                              const float* __restrict__ dinv,
                                              const float* __restrict__ b1,
                                              uint* __restrict__ h, int n) {
    int v = blockIdx.x * 4 + (threadIdx.x >> 6);
    if (v >= n) return;
    int lane = threadIdx.x & 63;
    uint u = hxs[v * 64 + lane];
    float a0 = bfl(u), a1 = bfh(u);
    int s = rp[v], e = s + deg[v];
    int i = s;
    for (; i + 3 < e; i += 4) {
        int s0 = csr_src[i], s1 = csr_src[i + 1];
        int s2 = csr_src[i + 2], s3 = csr_src[i + 3];
        uint u0 = hxs[s0 * 64 + lane], u1 = hxs[s1 * 64 + lane];
        uint u2 = hxs[s2 * 64 + lane], u3 = hxs[s3 * 64 + lane];
        a0 += bfl(u0) + bfl(u1) + bfl(u2) + bfl(u3);
        a1 += bfh(u0) + bfh(u1) + bfh(u2) + bfh(u3);
    }
    for (; i < e; i++) {
        uint u0 = hxs[csr_src[i] * 64 + lane];
        a0 += bfl(u0);
        a1 += bfh(u0);
    }
    float dv = dinv[v];
    float2 bb = ((const float2*)b1)[lane];
    float h0 = fmaxf(fmaf(dv, a0, bb.x), 0.f);
    float h1 = fmaxf(fmaf(dv, a1, bb.y), 0.f);
    h[v * 64 + lane] = (uint)f2bf(h0) | ((uint)f2bf(h1) << 16);
}

// ---------------- GEMM2 (MFMA): hx2s = bf16( dinv * (h @ W2) ) ----------------
__global__ __launch_bounds__(256) void k_gemm2(const ushort* __restrict__ h,
                                               const ushort* __restrict__ w2t,
                                               const float* __restrict__ dinv,
                                               ushort* __restrict__ hx2s, int n) {
    __shared__ ushort hs[128 * 136];
    __shared__ ushort ws[32 * 136];
    const int tid = threadIdx.x;
    const int w = tid >> 6, lane = tid & 63;
    const int lm = lane & 15, quad = lane >> 4;
    const int base = blockIdx.x * 128;

#pragma unroll
    for (int t = 0; t < 8; t++) {
        int f = tid + 256 * t;
        int node = f >> 4, k8 = f & 15;
        int gn = base + node;
        uint4 v = (gn < n) ? *(const uint4*)&h[(ll)gn * 128 + k8 * 8]
                           : make_uint4(0u, 0u, 0u, 0u);
        *(uint4*)&hs[node * 136 + k8 * 8] = v;
    }
#pragma unroll
    for (int t = 0; t < 2; t++) {
        int f = tid + 256 * t;
        int nn = f >> 4, k8 = f & 15;
        uint4 v = *(const uint4*)&w2t[nn * 128 + k8 * 8];
        *(uint4*)&ws[nn * 136 + k8 * 8] = v;
    }
    __syncthreads();

    frag_cd acc[2][2];
#pragma unroll
    for (int mt = 0; mt < 2; mt++)
#pragma unroll
        for (int nt = 0; nt < 2; nt++) acc[mt][nt] = (frag_cd){0.f, 0.f, 0.f, 0.f};

#pragma unroll
    for (int ks = 0; ks < 4; ks++) {
        int ko = ks * 32 + quad * 8;
        frag_ab a[2], b[2];
#pragma unroll
        for (int mt = 0; mt < 2; mt++)
            a[mt] = *(const frag_ab*)&hs[(w * 32 + mt * 16 + lm) * 136 + ko];
#pragma unroll
        for (int nt = 0; nt < 2; nt++)
            b[nt] = *(const frag_ab*)&ws[(nt * 16 + lm) * 136 + ko];
#pragma unroll
        for (int mt = 0; mt < 2; mt++)
#pragma unroll
            for (int nt = 0; nt < 2; nt++)
                acc[mt][nt] = __builtin_amdgcn_mfma_f32_16x16x32_bf16(
                    a[mt], b[nt], acc[mt][nt], 0, 0, 0);
    }
#pragma unroll
    for (int mt = 0; mt < 2; mt++) {
#pragma unroll
        for (int r = 0; r < 4; r++) {
            int node = base + w * 32 + mt * 16 + quad * 4 + r;
            if (node < n) {
                float dv = dinv[node];
#pragma unroll
                for (int nt = 0; nt < 2; nt++) {
                    int dim = nt * 16 + lm;
                    hx2s[(ll)node * D_OUT + dim] = f2bf(acc[mt][nt][r] * dv);
                }
            }
        }
    }
}

// ---------------- layer-2 gather + bias + log_softmax: 16 lanes per node ----------------
__global__ __launch_bounds__(256) void k_agg2(const uint* __restrict__ hx2s,
                                              const int* __restrict__ csr_src,
                                              const int* __restrict__ rp,
                                              const int* __restrict__ deg,
                                              const float* __restrict__ dinv,
                                              const float* __restrict__ b2,
                                              float2* __restrict__ out, int n) {
    int v = blockIdx.x * 16 + (threadIdx.x >> 4);
    if (v >= n) return;
    int l16 = threadIdx.x & 15;
    uint u = hx2s[v * 16 + l16];
    float a0 = bfl(u), a1 = bfh(u);
    int s = rp[v], e = s + deg[v];
    int i = s;
    for (; i + 3 < e; i += 4) {
        int s0 = csr_src[i], s1 = csr_src[i + 1];
        int s2 = csr_src[i + 2], s3 = csr_src[i + 3];
        uint u0 = hx2s[s0 * 16 + l16], u1 = hx2s[s1 * 16 + l16];
        uint u2 = hx2s[s2 * 16 + l16], u3 = hx2s[s3 * 16 + l16];
        a0 += bfl(u0) + bfl(u1) + bfl(u2) + bfl(u3);
        a1 += bfh(u0) + bfh(u1) + bfh(u2) + bfh(u3);
    }
    for (; i < e; i++) {
        uint u0 = hx2s[csr_src[i] * 16 + l16];
        a0 += bfl(u0);
        a1 += bfh(u0);
    }
    float dv = dinv[v];
    float2 bb = ((const float2*)b2)[l16];
    float t0 = fmaf(dv, a0, bb.x), t1 = fmaf(dv, a1, bb.y);
    float mx = fmaxf(t0, t1);
#pragma unroll
    for (int m = 8; m >= 1; m >>= 1) mx = fmaxf(mx, __shfl_xor(mx, m));
    float sum = __expf(t0 - mx) + __expf(t1 - mx);
#pragma unroll
    for (int m = 8; m >= 1; m >>= 1) sum += __shfl_xor(sum, m);
    float lse = mx + __logf(sum);
    out[v * 16 + l16] = make_float2(t0 - lse, t1 - lse);
}

extern "C" void kernel_launch(void* const* d_in, const int* in_sizes, int n_in,
                              void* d_out, int out_size, void* d_ws, size_t ws_size,
                              hipStream_t stream) {
    const float* x  = (const float*)d_in[0];
    const float* W1 = (const float*)d_in[1];
    const float* b1 = (const float*)d_in[2];
    const float* W2 = (const float*)d_in[3];
    const float* b2 = (const float*)d_in[4];
    const int*   ei = (const int*)d_in[5];
    const int* row = ei;
    const int* col = ei + N_EDGES;
    float* out = (float*)d_out;

    // ws layout (4B words): deg|rp [N_PAD each] | bsum[512] | gcur[256] | dinv[N_PAD] |
    //   csr_src[E] | pairs[E] | w1t(bf16) | w2t(bf16) | hxs(bf16 N*128) | h(bf16 N*128) | hx2s
    int*    ws_i    = (int*)d_ws;
    int*    deg     = ws_i;
    int*    rp      = ws_i + N_PAD;
    int*    bsum    = ws_i + 2 * N_PAD;
    int*    gcur    = ws_i + 2 * N_PAD + 512;
    float*  dinv    = (float*)(ws_i + 2 * N_PAD + 768);
    int*    csr_src = ws_i + 3 * N_PAD + 768;
    uint*   pairs   = (uint*)(csr_src + N_EDGES);
    ushort* w1t     = (ushort*)(pairs + N_EDGES);
    ushort* w2t     = w1t + D_IN * D_H;
    ushort* hxs     = w2t + D_H * D_OUT;
    ushort* h       = hxs + (ll)N_NODES * D_H;
    ushort* hx2s    = h + (ll)N_NODES * D_H;

    const int n = N_NODES, e = N_EDGES;
    const int nb = (n + 255) / 256;

    hipMemsetAsync(deg, 0, N_PAD * sizeof(int), stream);

    k_count<<<(e + 255) / 256, 256, 0, stream>>>(col, deg, e);
    k_scan1<<<nb, 256, 0, stream>>>(deg, rp, bsum, n);
    k_scan2<<<1, 512, 0, stream>>>(bsum, nb);
    k_finalize<<<nb, 256, 0, stream>>>(rp, bsum, deg, dinv, n);
    k_initcur<<<1, 256, 0, stream>>>(rp, gcur);
    k_bucketA<<<(e + CHUNK - 1) / CHUNK, 256, 0, stream>>>(row, col, gcur, pairs, e);
    k_bucketB<<<NB, 256, 0, stream>>>(pairs, rp, csr_src, e, n);
    k_prep_w<<<(D_IN * D_H + D_H * D_OUT + 255) / 256, 256, 0, stream>>>(W1, W2, w1t, w2t);

    k_gemm1<<<(n + 127) / 128, 256, 0, stream>>>(x, w1t, dinv, hxs, n);
    k_agg1<<<(n + 3) / 4, 256, 0, stream>>>((const uint*)hxs, csr_src, rp, deg, dinv, b1,
                                            (uint*)h, n);
    k_gemm2<<<(n + 127) / 128, 256, 0, stream>>>(h, w2t, dinv, hx2s, n);
    k_agg2<<<(n + 15) / 16, 256, 0, stream>>>((const uint*)hx2s, csr_src, rp, deg, dinv, b2,
                                              (float2*)out, n);
}

// Round 5
// 426.433 us; speedup vs baseline: 3.1077x; 1.0249x over previous
//
#include <hip/hip_runtime.h>
#include <math.h>

#define N_NODES 100000
#define N_EDGES 1600000
#define D_IN 256
#define D_H 128
#define D_OUT 32
#define N_PAD 102400
#define NB 196      // ceil(N_NODES / 512) buckets of 512 nodes
#define CHUNK 4096  // edges per pass-A block

typedef long long ll;
typedef unsigned int uint;
typedef unsigned short ushort;
typedef short frag_ab __attribute__((ext_vector_type(8)));   // 8 bf16
typedef float frag_cd __attribute__((ext_vector_type(4)));   // 4 f32

__device__ __forceinline__ ushort f2bf(float f) {            // RNE fp32->bf16
    uint u = __float_as_uint(f);
    u += 0x7FFFu + ((u >> 16) & 1u);
    return (ushort)(u >> 16);
}
__device__ __forceinline__ float bfl(uint u) { return __uint_as_float(u << 16); }
__device__ __forceinline__ float bfh(uint u) { return __uint_as_float(u & 0xFFFF0000u); }

// ---------------- degree histogram ----------------
__global__ void k_count(const int* __restrict__ col, int* __restrict__ deg, int e) {
    int i = blockIdx.x * blockDim.x + threadIdx.x;
    if (i < e) atomicAdd(&deg[col[i]], 1);
}

// ---------------- exclusive scan ----------------
__global__ void k_scan1(const int* __restrict__ deg, int* __restrict__ rp,
                        int* __restrict__ bsum, int n) {
    __shared__ int s[256];
    int i = blockIdx.x * 256 + threadIdx.x;
    int v = (i < n) ? deg[i] : 0;
    s[threadIdx.x] = v;
    __syncthreads();
    for (int off = 1; off < 256; off <<= 1) {
        int t = (threadIdx.x >= off) ? s[threadIdx.x - off] : 0;
        __syncthreads();
        s[threadIdx.x] += t;
        __syncthreads();
    }
    if (i < n) rp[i] = s[threadIdx.x] - v;
    if (threadIdx.x == 255) bsum[blockIdx.x] = s[255];
}

__global__ void k_scan2(int* __restrict__ bsum, int nb) {
    __shared__ int s[512];
    int v = (threadIdx.x < nb) ? bsum[threadIdx.x] : 0;
    s[threadIdx.x] = v;
    __syncthreads();
    for (int off = 1; off < 512; off <<= 1) {
        int t = (threadIdx.x >= off) ? s[threadIdx.x - off] : 0;
        __syncthreads();
        s[threadIdx.x] += t;
        __syncthreads();
    }
    if (threadIdx.x < nb) bsum[threadIdx.x] = s[threadIdx.x] - v;
}

__global__ void k_finalize(int* __restrict__ rp, const int* __restrict__ bsum,
                           const int* __restrict__ deg, float* __restrict__ dinv, int n) {
    int i = blockIdx.x * 256 + threadIdx.x;
    if (i < n) {
        rp[i] += bsum[i >> 8];
        dinv[i] = rsqrtf((float)(1 + deg[i]));
    }
}

// gcur[b] = start of bucket b's region in the CSR / pair arrays
__global__ void k_initcur(const int* __restrict__ rp, int* __restrict__ gcur) {
    int t = threadIdx.x;
    if (t < NB) gcur[t] = rp[t << 9];
}

// ---------------- pass A: bucket partition (packed row<<9 | local-node) ----------------
__global__ __launch_bounds__(256) void k_bucketA(const int* __restrict__ row,
                                                 const int* __restrict__ col,
                                                 int* __restrict__ gcur,
                                                 uint* __restrict__ pairs, int e) {
    __shared__ int cnt[NB];
    __shared__ int lstart[NB];
    const int t = threadIdx.x;
    for (int i = t; i < NB; i += 256) cnt[i] = 0;
    __syncthreads();
    const int base = blockIdx.x * CHUNK;
    int myc[CHUNK / 256];
#pragma unroll
    for (int j = 0; j < CHUNK / 256; j++) {
        int idx = base + t + j * 256;
        int c = (idx < e) ? col[idx] : -1;
        myc[j] = c;
        if (c >= 0) atomicAdd(&cnt[c >> 9], 1);
    }
    __syncthreads();
    for (int i = t; i < NB; i += 256) {
        int c = cnt[i];
        lstart[i] = (c > 0) ? atomicAdd(&gcur[i], c) : 0;
        cnt[i] = 0;  // reuse as local cursor
    }
    __syncthreads();
#pragma unroll
    for (int j = 0; j < CHUNK / 256; j++) {
        int c = myc[j];
        if (c >= 0) {
            int idx = base + t + j * 256;
            int b = c >> 9;
            int pos = lstart[b] + atomicAdd(&cnt[b], 1);
            pairs[pos] = ((uint)row[idx] << 9) | (uint)(c & 511);
        }
    }
}

// ---------------- pass B: per-bucket exact CSR fill (single-CU regions) ----------------
__global__ __launch_bounds__(256) void k_bucketB(const uint* __restrict__ pairs,
                                                 const int* __restrict__ rp,
                                                 int* __restrict__ csr_src, int e, int n) {
    __shared__ int cur[512];
    const int b = blockIdx.x;
    const int node0 = b << 9;
    const int nn = min(512, n - node0);
    const int t = threadIdx.x;
    for (int i = t; i < nn; i += 256) cur[i] = rp[node0 + i];
    __syncthreads();
    const int pb = rp[node0];
    const int pe = (node0 + 512 < n) ? rp[node0 + 512] : e;
    for (int i = pb + t; i < pe; i += 256) {
        uint p = pairs[i];
        int pos = atomicAdd(&cur[p & 511], 1);
        csr_src[pos] = (int)(p >> 9);
    }
}

// ---------------- weight transpose+convert: w1t[n][k], w2t[n][k] bf16 ----------------
__global__ void k_prep_w(const float* __restrict__ W1, const float* __restrict__ W2,
                         ushort* __restrict__ w1t, ushort* __restrict__ w2t) {
    int i = blockIdx.x * 256 + threadIdx.x;
    if (i < D_IN * D_H) {
        int k = i >> 7, nn = i & 127;
        w1t[nn * D_IN + k] = f2bf(W1[i]);
    } else if (i < D_IN * D_H + D_H * D_OUT) {
        int j = i - D_IN * D_H;
        int k = j >> 5, nn = j & 31;
        w2t[nn * D_H + k] = f2bf(W2[j]);
    }
}

// ---------------- GEMM1 (MFMA, LDS-free): hxs = bf16( dinv * (x @ W1) ) ----------------
// wave = 32 nodes x 128 dims; block = 4 waves = 128 nodes; no barriers.
// A direct from global fp32 x (cvt in-reg); B direct from L1/L2-resident w1t.
__global__ __launch_bounds__(256, 3) void k_gemm1(const float* __restrict__ x,
                                                  const ushort* __restrict__ w1t,
                                                  const float* __restrict__ dinv,
                                                  ushort* __restrict__ hxs, int n) {
    const int tid = threadIdx.x;
    const int wv = tid >> 6, lane = tid & 63;
    const int lm = lane & 15, quad = lane >> 4;
    const int base = blockIdx.x * 128 + wv * 32;

    frag_cd acc[2][8];
#pragma unroll
    for (int mt = 0; mt < 2; mt++)
#pragma unroll
        for (int nt = 0; nt < 8; nt++) acc[mt][nt] = (frag_cd){0.f, 0.f, 0.f, 0.f};

    // A-row base pointers (clamped; OOB rows produce garbage only in discarded outputs)
    const float4* xr[2];
#pragma unroll
    for (int mt = 0; mt < 2; mt++) {
        int node = base + mt * 16 + lm;
        xr[mt] = (const float4*)(x + (ll)min(node, n - 1) * D_IN);
    }

#pragma unroll
    for (int ks = 0; ks < 8; ks++) {       // K = 256 in chunks of 32
        frag_ab a[2];
#pragma unroll
        for (int mt = 0; mt < 2; mt++) {
            float4 v0 = xr[mt][ks * 8 + quad * 2];
            float4 v1 = xr[mt][ks * 8 + quad * 2 + 1];
            uint* ap = (uint*)&a[mt];
            ap[0] = (uint)f2bf(v0.x) | ((uint)f2bf(v0.y) << 16);
            ap[1] = (uint)f2bf(v0.z) | ((uint)f2bf(v0.w) << 16);
            ap[2] = (uint)f2bf(v1.x) | ((uint)f2bf(v1.y) << 16);
            ap[3] = (uint)f2bf(v1.z) | ((uint)f2bf(v1.w) << 16);
        }
#pragma unroll
        for (int nt = 0; nt < 8; nt++) {
            frag_ab b = *(const frag_ab*)&w1t[(nt * 16 + lm) * D_IN + ks * 32 + quad * 8];
#pragma unroll
            for (int mt = 0; mt < 2; mt++)
                acc[mt][nt] = __builtin_amdgcn_mfma_f32_16x16x32_bf16(
                    a[mt], b, acc[mt][nt], 0, 0, 0);
        }
    }

#pragma unroll
    for (int mt = 0; mt < 2; mt++) {
#pragma unroll
        for (int r = 0; r < 4; r++) {
            int node = base + mt * 16 + quad * 4 + r;
            if (node < n) {
                float dv = dinv[node];
#pragma unroll
                for (int nt = 0; nt < 8; nt++)
                    hxs[(ll)node * D_H + nt * 16 + lm] = f2bf(acc[mt][nt][r] * dv);
            }
        }
    }
}

// ---------------- layer-1 gather (bf16 rows): one wave per node ----------------
__global__ __launch_bounds__(256) void k_agg1(const uint* __restrict__ hxs,
                                              const int* __restrict__ csr_src,
                                              const int* __restrict__ rp,
                                              const int* __restrict__ deg,
                                              const float* __restrict__ dinv,
                                              const float* __restrict__ b1,
                                              uint* __restrict__ h, int n) {
    int v = blockIdx.x * 4 + (threadIdx.x >> 6);
    if (v >= n) return;
    int lane = threadIdx.x & 63;
    uint u = hxs[v * 64 + lane];
    float a0 = bfl(u), a1 = bfh(u);
    int s = rp[v], e = s + deg[v];
    int i = s;
    for (; i + 3 < e; i += 4) {
        int s0 = csr_src[i], s1 = csr_src[i + 1];
        int s2 = csr_src[i + 2], s3 = csr_src[i + 3];
        uint u0 = hxs[s0 * 64 + lane], u1 = hxs[s1 * 64 + lane];
        uint u2 = hxs[s2 * 64 + lane], u3 = hxs[s3 * 64 + lane];
        a0 += bfl(u0) + bfl(u1) + bfl(u2) + bfl(u3);
        a1 += bfh(u0) + bfh(u1) + bfh(u2) + bfh(u3);
    }
    for (; i < e; i++) {
        uint u0 = hxs[csr_src[i] * 64 + lane];
        a0 += bfl(u0);
        a1 += bfh(u0);
    }
    float dv = dinv[v];
    float2 bb = ((const float2*)b1)[lane];
    float h0 = fmaxf(fmaf(dv, a0, bb.x), 0.f);
    float h1 = fmaxf(fmaf(dv, a1, bb.y), 0.f);
    h[v * 64 + lane] = (uint)f2bf(h0) | ((uint)f2bf(h1) << 16);
}

// ---------------- GEMM2 (MFMA, LDS-free): hx2s = bf16( dinv * (h @ W2) ) ----------------
// wave = 32 nodes x 32 dims; block = 4 waves = 128 nodes; no barriers.
__global__ __launch_bounds__(256) void k_gemm2(const ushort* __restrict__ h,
                                               const ushort* __restrict__ w2t,
                                               const float* __restrict__ dinv,
                                               ushort* __restrict__ hx2s, int n) {
    const int tid = threadIdx.x;
    const int wv = tid >> 6, lane = tid & 63;
    const int lm = lane & 15, quad = lane >> 4;
    const int base = blockIdx.x * 128 + wv * 32;

    frag_cd acc[2][2];
#pragma unroll
    for (int mt = 0; mt < 2; mt++)
#pragma unroll
        for (int nt = 0; nt < 2; nt++) acc[mt][nt] = (frag_cd){0.f, 0.f, 0.f, 0.f};

    const ushort* hr[2];
#pragma unroll
    for (int mt = 0; mt < 2; mt++) {
        int node = base + mt * 16 + lm;
        hr[mt] = h + (ll)min(node, n - 1) * D_H;
    }

#pragma unroll
    for (int ks = 0; ks < 4; ks++) {       // K = 128 in chunks of 32
        frag_ab a[2], b[2];
#pragma unroll
        for (int mt = 0; mt < 2; mt++)
            a[mt] = *(const frag_ab*)&hr[mt][ks * 32 + quad * 8];
#pragma unroll
        for (int nt = 0; nt < 2; nt++)
            b[nt] = *(const frag_ab*)&w2t[(nt * 16 + lm) * D_H + ks * 32 + quad * 8];
#pragma unroll
        for (int mt = 0; mt < 2; mt++)
#pragma unroll
            for (int nt = 0; nt < 2; nt++)
                acc[mt][nt] = __builtin_amdgcn_mfma_f32_16x16x32_bf16(
                    a[mt], b[nt], acc[mt][nt], 0, 0, 0);
    }

#pragma unroll
    for (int mt = 0; mt < 2; mt++) {
#pragma unroll
        for (int r = 0; r < 4; r++) {
            int node = base + mt * 16 + quad * 4 + r;
            if (node < n) {
                float dv = dinv[node];
#pragma unroll
                for (int nt = 0; nt < 2; nt++)
                    hx2s[(ll)node * D_OUT + nt * 16 + lm] = f2bf(acc[mt][nt][r] * dv);
            }
        }
    }
}

// ---------------- layer-2 gather + bias + log_softmax: 16 lanes per node ----------------
__global__ __launch_bounds__(256) void k_agg2(const uint* __restrict__ hx2s,
                                              const int* __restrict__ csr_src,
                                              const int* __restrict__ rp,
                                              const int* __restrict__ deg,
                                              const float* __restrict__ dinv,
                                              const float* __restrict__ b2,
                                              float2* __restrict__ out, int n) {
    int v = blockIdx.x * 16 + (threadIdx.x >> 4);
    if (v >= n) return;
    int l16 = threadIdx.x & 15;
    uint u = hx2s[v * 16 + l16];
    float a0 = bfl(u), a1 = bfh(u);
    int s = rp[v], e = s + deg[v];
    int i = s;
    for (; i + 3 < e; i += 4) {
        int s0 = csr_src[i], s1 = csr_src[i + 1];
        int s2 = csr_src[i + 2], s3 = csr_src[i + 3];
        uint u0 = hx2s[s0 * 16 + l16], u1 = hx2s[s1 * 16 + l16];
        uint u2 = hx2s[s2 * 16 + l16], u3 = hx2s[s3 * 16 + l16];
        a0 += bfl(u0) + bfl(u1) + bfl(u2) + bfl(u3);
        a1 += bfh(u0) + bfh(u1) + bfh(u2) + bfh(u3);
    }
    for (; i < e; i++) {
        uint u0 = hx2s[csr_src[i] * 16 + l16];
        a0 += bfl(u0);
        a1 += bfh(u0);
    }
    float dv = dinv[v];
    float2 bb = ((const float2*)b2)[l16];
    float t0 = fmaf(dv, a0, bb.x), t1 = fmaf(dv, a1, bb.y);
    float mx = fmaxf(t0, t1);
#pragma unroll
    for (int m = 8; m >= 1; m >>= 1) mx = fmaxf(mx, __shfl_xor(mx, m));
    float sum = __expf(t0 - mx) + __expf(t1 - mx);
#pragma unroll
    for (int m = 8; m >= 1; m >>= 1) sum += __shfl_xor(sum, m);
    float lse = mx + __logf(sum);
    out[v * 16 + l16] = make_float2(t0 - lse, t1 - lse);
}

extern "C" void kernel_launch(void* const* d_in, const int* in_sizes, int n_in,
                              void* d_out, int out_size, void* d_ws, size_t ws_size,
                              hipStream_t stream) {
    const float* x  = (const float*)d_in[0];
    const float* W1 = (const float*)d_in[1];
    const float* b1 = (const float*)d_in[2];
    const float* W2 = (const float*)d_in[3];
    const float* b2 = (const float*)d_in[4];
    const int*   ei = (const int*)d_in[5];
    const int* row = ei;
    const int* col = ei + N_EDGES;
    float* out = (float*)d_out;

    // ws layout (4B words): deg|rp [N_PAD each] | bsum[512] | gcur[256] | dinv[N_PAD] |
    //   csr_src[E] | pairs[E] | w1t(bf16) | w2t(bf16) | hxs(bf16 N*128) | h(bf16 N*128) | hx2s
    int*    ws_i    = (int*)d_ws;
    int*    deg     = ws_i;
    int*    rp      = ws_i + N_PAD;
    int*    bsum    = ws_i + 2 * N_PAD;
    int*    gcur    = ws_i + 2 * N_PAD + 512;
    float*  dinv    = (float*)(ws_i + 2 * N_PAD + 768);
    int*    csr_src = ws_i + 3 * N_PAD + 768;
    uint*   pairs   = (uint*)(csr_src + N_EDGES);
    ushort* w1t     = (ushort*)(pairs + N_EDGES);
    ushort* w2t     = w1t + D_IN * D_H;
    ushort* hxs     = w2t + D_H * D_OUT;
    ushort* h       = hxs + (ll)N_NODES * D_H;
    ushort* hx2s    = h + (ll)N_NODES * D_H;

    const int n = N_NODES, e = N_EDGES;
    const int nb = (n + 255) / 256;

    hipMemsetAsync(deg, 0, N_PAD * sizeof(int), stream);

    k_count<<<(e + 255) / 256, 256, 0, stream>>>(col, deg, e);
    k_scan1<<<nb, 256, 0, stream>>>(deg, rp, bsum, n);
    k_scan2<<<1, 512, 0, stream>>>(bsum, nb);
    k_finalize<<<nb, 256, 0, stream>>>(rp, bsum, deg, dinv, n);
    k_initcur<<<1, 256, 0, stream>>>(rp, gcur);
    k_bucketA<<<(e + CHUNK - 1) / CHUNK, 256, 0, stream>>>(row, col, gcur, pairs, e);
    k_bucketB<<<NB, 256, 0, stream>>>(pairs, rp, csr_src, e, n);
    k_prep_w<<<(D_IN * D_H + D_H * D_OUT + 255) / 256, 256, 0, stream>>>(W1, W2, w1t, w2t);

    k_gemm1<<<(n + 127) / 128, 256, 0, stream>>>(x, w1t, dinv, hxs, n);
    k_agg1<<<(n + 3) / 4, 256, 0, stream>>>((const uint*)hxs, csr_src, rp, deg, dinv, b1,
                                            (uint*)h, n);
    k_gemm2<<<(n + 127) / 128, 256, 0, stream>>>(h, w2t, dinv, hx2s, n);
    k_agg2<<<(n + 15) / 16, 256, 0, stream>>>((const uint*)hx2s, csr_src, rp, deg, dinv, b2,
                                              (float2*)out, n);
}